// Round 3
// baseline (6314.906 us; speedup 1.0000x reference)
//
#include <hip/hip_runtime.h>
#include <hip/hip_bf16.h>
#include <cstdint>

// Problem constants (MoEExperts): x[4096,2048] f32, top-2 of 8 experts,
// w1/w3 [8,2048,4096], w2 [8,4096,2048], out [4096,2048] f32.
#define T_TOKENS 4096
#define HID      2048
#define INTER    4096
#define NEXP     8
#define TOPK     2
#define NPAIRS   (T_TOKENS * TOPK)          // 8192
#define BM 64
#define BN 64
#define BK 16
#define MAXROWS  (NPAIRS + NEXP * BM)       // per-expert lists padded to BM

// ---------------- routing: build per-expert compact token lists ------------
__global__ void route_kernel(const int* __restrict__ eidx,
                             const float* __restrict__ ew,
                             int* __restrict__ cnt, int* __restrict__ pbase,
                             int* __restrict__ tokl, float* __restrict__ wgtl) {
    __shared__ int s_cnt[NEXP];
    __shared__ int s_pos[NEXP];
    __shared__ int s_base[NEXP];
    int tid = threadIdx.x;
    if (tid < NEXP) { s_cnt[tid] = 0; s_pos[tid] = 0; }
    __syncthreads();
    for (int p = tid; p < NPAIRS; p += blockDim.x)
        atomicAdd(&s_cnt[eidx[p]], 1);
    __syncthreads();
    if (tid == 0) {
        int b = 0;
        for (int e = 0; e < NEXP; ++e) {
            s_base[e] = b;
            cnt[e]    = s_cnt[e];
            pbase[e]  = b;
            b += (s_cnt[e] + BM - 1) / BM * BM;   // pad to tile boundary
        }
        pbase[NEXP] = b;
    }
    __syncthreads();
    for (int p = tid; p < NPAIRS; p += blockDim.x) {
        int e   = eidx[p];
        int pos = atomicAdd(&s_pos[e], 1);
        tokl[s_base[e] + pos] = p >> 1;           // token = p / TOPK (TOPK==2)
        wgtl[s_base[e] + pos] = ew[p];
    }
}

// ---------------- phase 1: h = silu(x@w1) * (x@w3) for one INTER chunk -----
__global__ __launch_bounds__(256) void ffn1_kernel(
        const float* __restrict__ x,
        const float* __restrict__ w1,
        const float* __restrict__ w3,
        const int* __restrict__ cnt, const int* __restrict__ pbase,
        const int* __restrict__ tokl,
        float* __restrict__ h, int chunk, int bi) {
    int e  = blockIdx.z;
    int ce = cnt[e];
    int r0 = blockIdx.y * BM;
    if (r0 >= ce) return;
    int base = pbase[e];
    long gcol = (long)chunk * bi + blockIdx.x * BN;

    __shared__ float As[BM][BK + 1];
    __shared__ float B1[BK][BN];
    __shared__ float B2[BK][BN];

    int tid = threadIdx.x;
    int tx = tid & 15, ty = tid >> 4;

    float accg[4][4] = {{0.f}};
    float accu[4][4] = {{0.f}};

    const float* w1p = w1 + (size_t)e * HID * INTER + gcol;
    const float* w3p = w3 + (size_t)e * HID * INTER + gcol;

    for (int k0 = 0; k0 < HID; k0 += BK) {
        #pragma unroll
        for (int i = 0; i < 4; ++i) {
            int idx = tid + i * 256;
            int m = idx >> 4, k = idx & 15;
            int r = r0 + m;
            float v = 0.f;
            if (r < ce) {
                int tok = tokl[base + r];
                v = x[(size_t)tok * HID + k0 + k];
            }
            As[m][k] = v;
        }
        #pragma unroll
        for (int i = 0; i < 4; ++i) {
            int idx = tid + i * 256;
            int k = idx >> 6, n = idx & 63;
            size_t off = (size_t)(k0 + k) * INTER + n;
            B1[k][n] = w1p[off];
            B2[k][n] = w3p[off];
        }
        __syncthreads();
        #pragma unroll
        for (int kk = 0; kk < BK; ++kk) {
            float a[4], b1[4], b2[4];
            #pragma unroll
            for (int mm = 0; mm < 4; ++mm) a[mm] = As[ty * 4 + mm][kk];
            #pragma unroll
            for (int nn = 0; nn < 4; ++nn) { b1[nn] = B1[kk][tx * 4 + nn]; b2[nn] = B2[kk][tx * 4 + nn]; }
            #pragma unroll
            for (int mm = 0; mm < 4; ++mm)
                #pragma unroll
                for (int nn = 0; nn < 4; ++nn) {
                    accg[mm][nn] += a[mm] * b1[nn];
                    accu[mm][nn] += a[mm] * b2[nn];
                }
        }
        __syncthreads();
    }
    #pragma unroll
    for (int mm = 0; mm < 4; ++mm) {
        int r = r0 + ty * 4 + mm;
        if (r >= ce) continue;
        float* hp = h + (size_t)(base + r) * bi + blockIdx.x * BN + tx * 4;
        #pragma unroll
        for (int nn = 0; nn < 4; ++nn) {
            float g = accg[mm][nn];
            float s = g / (1.f + __expf(-g));     // silu
            hp[nn] = s * accu[mm][nn];
        }
    }
}

// ---------------- phase 2: out += wgt * (h @ w2_chunk) ---------------------
__global__ __launch_bounds__(256) void ffn2_kernel(
        const float* __restrict__ h,
        const float* __restrict__ w2,
        const int* __restrict__ cnt, const int* __restrict__ pbase,
        const int* __restrict__ tokl, const float* __restrict__ wgtl,
        float* __restrict__ out, int chunk, int bi) {
    int e  = blockIdx.z;
    int ce = cnt[e];
    int r0 = blockIdx.y * BM;
    if (r0 >= ce) return;
    int base = pbase[e];
    int gcol = blockIdx.x * BN;

    __shared__ float As[BM][BK + 1];
    __shared__ float Bs[BK][BN];

    int tid = threadIdx.x;
    int tx = tid & 15, ty = tid >> 4;
    float acc[4][4] = {{0.f}};

    const float* w2p = w2 + ((size_t)e * INTER + (size_t)chunk * bi) * HID + gcol;

    for (int k0 = 0; k0 < bi; k0 += BK) {
        #pragma unroll
        for (int i = 0; i < 4; ++i) {
            int idx = tid + i * 256;
            int m = idx >> 4, k = idx & 15;
            int r = r0 + m;
            As[m][k] = (r < ce) ? h[(size_t)(base + r) * bi + k0 + k] : 0.f;
        }
        #pragma unroll
        for (int i = 0; i < 4; ++i) {
            int idx = tid + i * 256;
            int k = idx >> 6, n = idx & 63;
            Bs[k][n] = w2p[(size_t)(k0 + k) * HID + n];
        }
        __syncthreads();
        #pragma unroll
        for (int kk = 0; kk < BK; ++kk) {
            float a[4], b[4];
            #pragma unroll
            for (int mm = 0; mm < 4; ++mm) a[mm] = As[ty * 4 + mm][kk];
            #pragma unroll
            for (int nn = 0; nn < 4; ++nn) b[nn] = Bs[kk][tx * 4 + nn];
            #pragma unroll
            for (int mm = 0; mm < 4; ++mm)
                #pragma unroll
                for (int nn = 0; nn < 4; ++nn)
                    acc[mm][nn] += a[mm] * b[nn];
        }
        __syncthreads();
    }
    #pragma unroll
    for (int mm = 0; mm < 4; ++mm) {
        int r = r0 + ty * 4 + mm;
        if (r >= ce) continue;
        int tok  = tokl[base + r];
        float wv = wgtl[base + r];
        float* op = out + (size_t)tok * HID + gcol + tx * 4;
        #pragma unroll
        for (int nn = 0; nn < 4; ++nn)
            atomicAdd(&op[nn], wv * acc[mm][nn]);
    }
}

extern "C" void kernel_launch(void* const* d_in, const int* in_sizes, int n_in,
                              void* d_out, int out_size, void* d_ws, size_t ws_size,
                              hipStream_t stream) {
    const float* x   = (const float*)d_in[0];
    const float* ew  = (const float*)d_in[1];
    const float* w1  = (const float*)d_in[2];
    const float* w2  = (const float*)d_in[3];
    const float* w3  = (const float*)d_in[4];
    const int*  eidx = (const int*)d_in[5];
    float* out = (float*)d_out;

    int*   cnt   = (int*)d_ws;
    int*   pbase = cnt + 8;            // 9 entries
    int*   tokl  = cnt + 32;           // byte offset 128
    float* wgtl  = (float*)(tokl + MAXROWS);
    float* h     = (float*)((((uintptr_t)(wgtl + MAXROWS)) + 255) & ~(uintptr_t)255);

    // choose largest INTER chunk that fits in workspace
    size_t head = (uintptr_t)h - (uintptr_t)d_ws;
    int bi = 64;
    for (int cand = 4096; cand >= 64; cand >>= 1) {
        if (head + (size_t)MAXROWS * cand * sizeof(float) <= ws_size) { bi = cand; break; }
    }
    int nchunk = INTER / bi;

    hipMemsetAsync(d_out, 0, (size_t)T_TOKENS * HID * sizeof(float), stream);
    route_kernel<<<1, 256, 0, stream>>>(eidx, ew, cnt, pbase, tokl, wgtl);

    for (int c = 0; c < nchunk; ++c) {
        ffn1_kernel<<<dim3(bi / BN, NPAIRS / BM, NEXP), 256, 0, stream>>>(
            x, w1, w3, cnt, pbase, tokl, h, c, bi);
        ffn2_kernel<<<dim3(HID / BN, NPAIRS / BM, NEXP), 256, 0, stream>>>(
            h, w2, cnt, pbase, tokl, wgtl, out, c, bi);
    }
}

// Round 4
// 1726.994 us; speedup vs baseline: 3.6566x; 3.6566x over previous
//
#include <hip/hip_runtime.h>
#include <hip/hip_bf16.h>
#include <cstdint>

// MoEExperts: x[4096,2048] f32, top-2 of 8 experts,
// w1/w3 [8,2048,4096] (K-major [K][N]), w2 [8,4096,2048], out [4096,2048] f32.
#define T_TOKENS 4096
#define HID      2048
#define INTER    4096
#define NEXP     8
#define TOPK     2
#define NPAIRS   (T_TOKENS * TOPK)          // 8192
#define BM 128
#define BN 128
#define BK 32
#define MAXROWS  (NPAIRS + NEXP * BM)       // 9216, per-expert lists padded
#define LSTR 40                             // ushorts per LDS row (80 B: 64B data + 16B pad)

typedef __attribute__((ext_vector_type(8))) short   short8;   // 8 bf16 (4 VGPRs)
typedef __attribute__((ext_vector_type(4))) float   f32x4;    // MFMA C/D
typedef __attribute__((ext_vector_type(8))) ushort  ushort8v;

static __device__ __forceinline__ ushort f2bf(float f) {
    __hip_bfloat16 b = __float2bfloat16(f);   // RNE
    return __builtin_bit_cast(ushort, b);
}

// ---------------- routing: per-expert compact token lists + pair->row map ---
__global__ void route_kernel(const int* __restrict__ eidx,
                             const float* __restrict__ ew,
                             int* __restrict__ cnt, int* __restrict__ pbase,
                             int* __restrict__ tokl, float* __restrict__ wgtl,
                             int* __restrict__ pairrow) {
    __shared__ int s_cnt[NEXP];
    __shared__ int s_pos[NEXP];
    __shared__ int s_base[NEXP];
    int tid = threadIdx.x;
    if (tid < NEXP) { s_cnt[tid] = 0; s_pos[tid] = 0; }
    __syncthreads();
    for (int p = tid; p < NPAIRS; p += blockDim.x)
        atomicAdd(&s_cnt[eidx[p]], 1);
    __syncthreads();
    if (tid == 0) {
        int b = 0;
        for (int e = 0; e < NEXP; ++e) {
            s_base[e] = b;
            cnt[e]    = s_cnt[e];
            pbase[e]  = b;
            b += (s_cnt[e] + BM - 1) / BM * BM;
        }
        pbase[NEXP] = b;
    }
    __syncthreads();
    for (int p = tid; p < NPAIRS; p += blockDim.x) {
        int e   = eidx[p];
        int pos = atomicAdd(&s_pos[e], 1);
        int row = s_base[e] + pos;
        tokl[row]   = p >> 1;                 // token = p / TOPK (TOPK==2)
        wgtl[row]   = ew[p];
        pairrow[p]  = row;
    }
}

// ---------------- ffn1: h = silu(x@w1) * (x@w3), bf16 MFMA ------------------
// grid: (row-blocks, INTER/BN, expert). Row-blocks in x so consecutive blocks
// share the same weight tiles (L2 reuse on the 805 MB of fp32 weights).
__global__ __launch_bounds__(256, 2) void ffn1_kernel(
        const float* __restrict__ x,
        const float* __restrict__ w1,
        const float* __restrict__ w3,
        const int* __restrict__ cnt, const int* __restrict__ pbase,
        const int* __restrict__ tokl,
        ushort* __restrict__ h) {
    int e  = blockIdx.z;
    int ce = cnt[e];
    int r0 = blockIdx.x * BM;
    if (r0 >= ce) return;
    int base = pbase[e];
    int c0   = blockIdx.y * BN;

    __shared__ ushort As[BM * LSTR];
    __shared__ ushort B1[BN * LSTR];
    __shared__ ushort B2[BN * LSTR];

    int tid  = threadIdx.x;
    int lane = tid & 63;
    int wid  = tid >> 6;
    int wr   = (wid >> 1) * 64;          // wave row offset in tile
    int wc   = (wid & 1)  * 64;          // wave col offset in tile

    // A staging coords: 8 threads x float4 per row, 32 rows per pass, 4 passes
    int ar = tid >> 3;                   // 0..31
    int ak = (tid & 7) * 4;              // 0..28
    const float* xr[4]; bool av[4];
    #pragma unroll
    for (int mi = 0; mi < 4; ++mi) {
        int r = r0 + ar + 32 * mi;
        av[mi] = (r < ce);
        xr[mi] = av[mi] ? (x + (size_t)tokl[base + r] * HID + ak) : x;
    }
    // B staging coords: transpose-load, thread t covers col n = t&127,
    // k-group bg = (t>>7)*8; two passes of 16 k each.
    int bn = tid & 127;
    int bg = (tid >> 7) * 8;
    const float* w1p = w1 + (size_t)e * HID * INTER + c0 + bn;
    const float* w3p = w3 + (size_t)e * HID * INTER + c0 + bn;

    f32x4 accg[4][4], accu[4][4];
    #pragma unroll
    for (int i = 0; i < 4; ++i)
        #pragma unroll
        for (int j = 0; j < 4; ++j) { accg[i][j] = (f32x4)0.f; accu[i][j] = (f32x4)0.f; }

    for (int k0 = 0; k0 < HID; k0 += BK) {
        // ---- stage A (gathered x rows), fp32 -> bf16
        #pragma unroll
        for (int mi = 0; mi < 4; ++mi) {
            ushort4 pk = make_ushort4(0, 0, 0, 0);
            if (av[mi]) {
                float4 v = *reinterpret_cast<const float4*>(xr[mi] + k0);
                pk.x = f2bf(v.x); pk.y = f2bf(v.y); pk.z = f2bf(v.z); pk.w = f2bf(v.w);
            }
            *reinterpret_cast<ushort4*>(&As[(ar + 32 * mi) * LSTR + ak]) = pk;
        }
        // ---- stage B1/B2 transposed ([n][k]), fp32 -> bf16
        #pragma unroll
        for (int g2 = 0; g2 < 2; ++g2) {
            int kk = k0 + g2 * 16 + bg;
            const float* p1 = w1p + (size_t)kk * INTER;
            const float* p3 = w3p + (size_t)kk * INTER;
            ushort8v t1, t3;
            #pragma unroll
            for (int j = 0; j < 8; ++j) {
                t1[j] = f2bf(p1[(size_t)j * INTER]);
                t3[j] = f2bf(p3[(size_t)j * INTER]);
            }
            *reinterpret_cast<ushort8v*>(&B1[bn * LSTR + g2 * 16 + bg]) = t1;
            *reinterpret_cast<ushort8v*>(&B2[bn * LSTR + g2 * 16 + bg]) = t3;
        }
        __syncthreads();
        // ---- fragments + MFMA
        int arow = wr + (lane & 15);
        int koff = (lane >> 4) * 8;
        short8 af[4];
        #pragma unroll
        for (int mi = 0; mi < 4; ++mi)
            af[mi] = *reinterpret_cast<const short8*>(&As[(arow + mi * 16) * LSTR + koff]);
        #pragma unroll
        for (int ni = 0; ni < 4; ++ni) {
            int brow = wc + ni * 16 + (lane & 15);
            short8 b1 = *reinterpret_cast<const short8*>(&B1[brow * LSTR + koff]);
            short8 b2 = *reinterpret_cast<const short8*>(&B2[brow * LSTR + koff]);
            #pragma unroll
            for (int mi = 0; mi < 4; ++mi) {
                accg[mi][ni] = __builtin_amdgcn_mfma_f32_16x16x32_bf16(af[mi], b1, accg[mi][ni], 0, 0, 0);
                accu[mi][ni] = __builtin_amdgcn_mfma_f32_16x16x32_bf16(af[mi], b2, accu[mi][ni], 0, 0, 0);
            }
        }
        __syncthreads();
    }

    // ---- epilogue: silu(g)*u -> bf16 h
    int colb = c0 + wc + (lane & 15);
    #pragma unroll
    for (int mi = 0; mi < 4; ++mi) {
        #pragma unroll
        for (int q = 0; q < 4; ++q) {
            int r = r0 + wr + mi * 16 + (lane >> 4) * 4 + q;
            if (r >= ce) continue;
            ushort* hp = h + (size_t)(base + r) * INTER + colb;
            #pragma unroll
            for (int ni = 0; ni < 4; ++ni) {
                float g = accg[mi][ni][q];
                float u = accu[mi][ni][q];
                float s = g / (1.f + __expf(-g));
                hp[ni * 16] = f2bf(s * u);
            }
        }
    }
}

// ---------------- ffn2: y = wgt * (h @ w2), bf16 MFMA -----------------------
__global__ __launch_bounds__(256, 2) void ffn2_kernel(
        const ushort* __restrict__ h,
        const float* __restrict__ w2,
        const int* __restrict__ cnt, const int* __restrict__ pbase,
        const float* __restrict__ wgtl,
        ushort* __restrict__ y) {
    int e  = blockIdx.z;
    int ce = cnt[e];
    int r0 = blockIdx.x * BM;
    if (r0 >= ce) return;
    int base = pbase[e];
    int c0   = blockIdx.y * BN;

    __shared__ ushort As[BM * LSTR];
    __shared__ ushort Bs[BN * LSTR];

    int tid  = threadIdx.x;
    int lane = tid & 63;
    int wid  = tid >> 6;
    int wr   = (wid >> 1) * 64;
    int wc   = (wid & 1)  * 64;

    // A staging: h is already bf16; 4 threads x 16B per row, 64 rows/pass
    int ar = tid >> 2;                    // 0..63
    int ak = (tid & 3) * 8;               // 0,8,16,24 (elements)
    const ushort* hr[2]; bool av[2];
    #pragma unroll
    for (int mi = 0; mi < 2; ++mi) {
        int r = r0 + ar + 64 * mi;
        av[mi] = (r < ce);
        hr[mi] = h + (size_t)(base + r) * INTER + ak;
    }
    int bn = tid & 127;
    int bg = (tid >> 7) * 8;
    const float* w2p = w2 + (size_t)e * INTER * HID + c0 + bn;

    f32x4 acc[4][4];
    #pragma unroll
    for (int i = 0; i < 4; ++i)
        #pragma unroll
        for (int j = 0; j < 4; ++j) acc[i][j] = (f32x4)0.f;

    for (int k0 = 0; k0 < INTER; k0 += BK) {
        #pragma unroll
        for (int mi = 0; mi < 2; ++mi) {
            uint4 v = make_uint4(0, 0, 0, 0);
            if (av[mi]) v = *reinterpret_cast<const uint4*>(hr[mi] + k0);
            *reinterpret_cast<uint4*>(&As[(ar + 64 * mi) * LSTR + ak]) = v;
        }
        #pragma unroll
        for (int g2 = 0; g2 < 2; ++g2) {
            int kk = k0 + g2 * 16 + bg;
            const float* p = w2p + (size_t)kk * HID;
            ushort8v t;
            #pragma unroll
            for (int j = 0; j < 8; ++j) t[j] = f2bf(p[(size_t)j * HID]);
            *reinterpret_cast<ushort8v*>(&Bs[bn * LSTR + g2 * 16 + bg]) = t;
        }
        __syncthreads();
        int arow = wr + (lane & 15);
        int koff = (lane >> 4) * 8;
        short8 af[4];
        #pragma unroll
        for (int mi = 0; mi < 4; ++mi)
            af[mi] = *reinterpret_cast<const short8*>(&As[(arow + mi * 16) * LSTR + koff]);
        #pragma unroll
        for (int ni = 0; ni < 4; ++ni) {
            int brow = wc + ni * 16 + (lane & 15);
            short8 b = *reinterpret_cast<const short8*>(&Bs[brow * LSTR + koff]);
            #pragma unroll
            for (int mi = 0; mi < 4; ++mi)
                acc[mi][ni] = __builtin_amdgcn_mfma_f32_16x16x32_bf16(af[mi], b, acc[mi][ni], 0, 0, 0);
        }
        __syncthreads();
    }

    int colb = c0 + wc + (lane & 15);
    #pragma unroll
    for (int mi = 0; mi < 4; ++mi) {
        #pragma unroll
        for (int q = 0; q < 4; ++q) {
            int r = r0 + wr + mi * 16 + (lane >> 4) * 4 + q;
            if (r >= ce) continue;
            float wv = wgtl[base + r];
            ushort* yp = y + (size_t)(base + r) * HID + colb;
            #pragma unroll
            for (int ni = 0; ni < 4; ++ni)
                yp[ni * 16] = f2bf(wv * acc[mi][ni][q]);
        }
    }
}

// ---------------- combine: out[t] = y[row(t,0)] + y[row(t,1)] --------------
__global__ __launch_bounds__(256) void combine_kernel(
        const ushort* __restrict__ y, const int* __restrict__ pairrow,
        float* __restrict__ out) {
    int t = blockIdx.x;
    const ushort* y0 = y + (size_t)pairrow[2 * t] * HID;
    const ushort* y1 = y + (size_t)pairrow[2 * t + 1] * HID;
    float* op = out + (size_t)t * HID;
    int c = threadIdx.x * 8;
    uint4 a = *reinterpret_cast<const uint4*>(y0 + c);
    uint4 b = *reinterpret_cast<const uint4*>(y1 + c);
    const uint* au = reinterpret_cast<const uint*>(&a);
    const uint* bu = reinterpret_cast<const uint*>(&b);
    #pragma unroll
    for (int i = 0; i < 4; ++i) {
        float alo = __builtin_bit_cast(float, au[i] << 16);
        float ahi = __builtin_bit_cast(float, au[i] & 0xffff0000u);
        float blo = __builtin_bit_cast(float, bu[i] << 16);
        float bhi = __builtin_bit_cast(float, bu[i] & 0xffff0000u);
        op[c + 2 * i]     = alo + blo;
        op[c + 2 * i + 1] = ahi + bhi;
    }
}

extern "C" void kernel_launch(void* const* d_in, const int* in_sizes, int n_in,
                              void* d_out, int out_size, void* d_ws, size_t ws_size,
                              hipStream_t stream) {
    (void)in_sizes; (void)n_in; (void)out_size; (void)ws_size;
    const float* x   = (const float*)d_in[0];
    const float* ew  = (const float*)d_in[1];
    const float* w1  = (const float*)d_in[2];
    const float* w2  = (const float*)d_in[3];
    const float* w3  = (const float*)d_in[4];
    const int*  eidx = (const int*)d_in[5];
    float* out = (float*)d_out;

    int*   cnt     = (int*)d_ws;
    int*   pbase   = cnt + 8;                 // 9 entries
    int*   tokl    = cnt + 32;                // MAXROWS
    float* wgtl    = (float*)(tokl + MAXROWS);
    int*   pairrow = (int*)(wgtl + MAXROWS);  // NPAIRS
    ushort* h = (ushort*)((((uintptr_t)(pairrow + NPAIRS)) + 255) & ~(uintptr_t)255);
    ushort* y = h + (size_t)MAXROWS * INTER;  // total ws use ~113.5 MB

    route_kernel<<<1, 256, 0, stream>>>(eidx, ew, cnt, pbase, tokl, wgtl, pairrow);
    ffn1_kernel<<<dim3(MAXROWS / BM, INTER / BN, NEXP), 256, 0, stream>>>(
        x, w1, w3, cnt, pbase, tokl, h);
    ffn2_kernel<<<dim3(MAXROWS / BM, HID / BN, NEXP), 256, 0, stream>>>(
        h, w2, cnt, pbase, wgtl, y);
    combine_kernel<<<T_TOKENS, 256, 0, stream>>>(y, pairrow, out);
}

// Round 5
// 1327.844 us; speedup vs baseline: 4.7558x; 1.3006x over previous
//
#include <hip/hip_runtime.h>
#include <hip/hip_bf16.h>
#include <cstdint>

// MoEExperts: x[4096,2048] f32, top-2 of 8 experts,
// w1/w3 [8,2048,4096] (K-major [K][N]), w2 [8,4096,2048], out [4096,2048] f32.
#define T_TOKENS 4096
#define HID      2048
#define INTER    4096
#define NEXP     8
#define TOPK     2
#define NPAIRS   (T_TOKENS * TOPK)          // 8192
#define BM 128
#define BN 128
#define BK 32
#define MAXROWS  (NPAIRS + NEXP * BM)       // 9216, per-expert lists padded
#define NRB      (MAXROWS / BM)             // 72 row-blocks
#define LSTR 40                             // ushorts per LDS row (80 B)

typedef __attribute__((ext_vector_type(8))) short   short8;   // 8 bf16 (4 VGPRs)
typedef __attribute__((ext_vector_type(4))) float   f32x4;    // MFMA C/D
typedef __attribute__((ext_vector_type(8))) ushort  ushort8v;

static __device__ __forceinline__ ushort f2bf(float f) {
    __hip_bfloat16 b = __float2bfloat16(f);   // RNE
    return __builtin_bit_cast(ushort, b);
}

// ---------------- routing: per-expert compact token lists + pair->row map ---
__global__ void route_kernel(const int* __restrict__ eidx,
                             const float* __restrict__ ew,
                             int* __restrict__ cnt, int* __restrict__ pbase,
                             int* __restrict__ tokl, float* __restrict__ wgtl,
                             int* __restrict__ pairrow) {
    __shared__ int s_cnt[NEXP];
    __shared__ int s_pos[NEXP];
    __shared__ int s_base[NEXP];
    int tid = threadIdx.x;
    if (tid < NEXP) { s_cnt[tid] = 0; s_pos[tid] = 0; }
    __syncthreads();
    for (int p = tid; p < NPAIRS; p += blockDim.x)
        atomicAdd(&s_cnt[eidx[p]], 1);
    __syncthreads();
    if (tid == 0) {
        int b = 0;
        for (int e = 0; e < NEXP; ++e) {
            s_base[e] = b;
            cnt[e]    = s_cnt[e];
            pbase[e]  = b;
            b += (s_cnt[e] + BM - 1) / BM * BM;
        }
        pbase[NEXP] = b;
    }
    __syncthreads();
    for (int p = tid; p < NPAIRS; p += blockDim.x) {
        int e   = eidx[p];
        int pos = atomicAdd(&s_pos[e], 1);
        int row = s_base[e] + pos;
        tokl[row]   = p >> 1;                 // token = p / TOPK (TOPK==2)
        wgtl[row]   = ew[p];
        pairrow[p]  = row;
    }
}

// ---------------- ffn1: h = silu(x@w1) * (x@w3), bf16 MFMA ------------------
// 1D grid, XCD-group swizzle: all row-blocks of one (colblock, expert) group
// land on the SAME XCD so the 2 MB weight strip is fetched into one L2 once.
__global__ __launch_bounds__(256, 2) void ffn1_kernel(
        const float* __restrict__ x,
        const float* __restrict__ w1,
        const float* __restrict__ w3,
        const int* __restrict__ cnt, const int* __restrict__ pbase,
        const int* __restrict__ tokl,
        ushort* __restrict__ h) {
    // decode: d%8 = XCD = group%8; group = colblock + 32*expert (256 groups)
    int d   = blockIdx.x;
    int xcd = d & 7;
    int q   = d >> 3;
    int gq  = q / NRB;
    int rb  = q % NRB;
    int g   = gq * 8 + xcd;
    int cb  = g & 31;          // 32 colblocks
    int e   = g >> 5;          // expert

    int ce = cnt[e];
    int r0 = rb * BM;
    if (r0 >= ce) return;
    int base = pbase[e];
    int c0   = cb * BN;

    __shared__ ushort As[BM * LSTR];
    __shared__ ushort B1[BN * LSTR];
    __shared__ ushort B2[BN * LSTR];

    int tid  = threadIdx.x;
    int lane = tid & 63;
    int wid  = tid >> 6;
    int wr   = (wid >> 1) * 64;          // wave row offset in tile
    int wc   = (wid & 1)  * 64;          // wave col offset in tile

    // A staging coords: 8 threads x float4 per row, 32 rows per pass, 4 passes
    int ar = tid >> 3;                   // 0..31
    int ak = (tid & 7) * 4;              // 0..28
    const float* xr[4]; bool av[4];
    #pragma unroll
    for (int mi = 0; mi < 4; ++mi) {
        int r = r0 + ar + 32 * mi;
        av[mi] = (r < ce);
        xr[mi] = av[mi] ? (x + (size_t)tokl[base + r] * HID + ak) : x;
    }
    // B staging coords: transpose-load, thread t covers col n = t&127,
    // k-group bg = (t>>7)*8; two passes of 16 k each.
    int bn = tid & 127;
    int bg = (tid >> 7) * 8;
    const float* w1p = w1 + (size_t)e * HID * INTER + c0 + bn;
    const float* w3p = w3 + (size_t)e * HID * INTER + c0 + bn;

    f32x4 accg[4][4], accu[4][4];
    #pragma unroll
    for (int i = 0; i < 4; ++i)
        #pragma unroll
        for (int j = 0; j < 4; ++j) { accg[i][j] = (f32x4)0.f; accu[i][j] = (f32x4)0.f; }

    for (int k0 = 0; k0 < HID; k0 += BK) {
        // ---- stage A (gathered x rows), fp32 -> bf16
        #pragma unroll
        for (int mi = 0; mi < 4; ++mi) {
            ushort4 pk = make_ushort4(0, 0, 0, 0);
            if (av[mi]) {
                float4 v = *reinterpret_cast<const float4*>(xr[mi] + k0);
                pk.x = f2bf(v.x); pk.y = f2bf(v.y); pk.z = f2bf(v.z); pk.w = f2bf(v.w);
            }
            *reinterpret_cast<ushort4*>(&As[(ar + 32 * mi) * LSTR + ak]) = pk;
        }
        // ---- stage B1/B2 transposed ([n][k]), fp32 -> bf16
        #pragma unroll
        for (int g2 = 0; g2 < 2; ++g2) {
            int kk = k0 + g2 * 16 + bg;
            const float* p1 = w1p + (size_t)kk * INTER;
            const float* p3 = w3p + (size_t)kk * INTER;
            ushort8v t1, t3;
            #pragma unroll
            for (int j = 0; j < 8; ++j) {
                t1[j] = f2bf(p1[(size_t)j * INTER]);
                t3[j] = f2bf(p3[(size_t)j * INTER]);
            }
            *reinterpret_cast<ushort8v*>(&B1[bn * LSTR + g2 * 16 + bg]) = t1;
            *reinterpret_cast<ushort8v*>(&B2[bn * LSTR + g2 * 16 + bg]) = t3;
        }
        __syncthreads();
        // ---- fragments + MFMA
        int arow = wr + (lane & 15);
        int koff = (lane >> 4) * 8;
        short8 af[4];
        #pragma unroll
        for (int mi = 0; mi < 4; ++mi)
            af[mi] = *reinterpret_cast<const short8*>(&As[(arow + mi * 16) * LSTR + koff]);
        #pragma unroll
        for (int ni = 0; ni < 4; ++ni) {
            int brow = wc + ni * 16 + (lane & 15);
            short8 b1 = *reinterpret_cast<const short8*>(&B1[brow * LSTR + koff]);
            short8 b2 = *reinterpret_cast<const short8*>(&B2[brow * LSTR + koff]);
            #pragma unroll
            for (int mi = 0; mi < 4; ++mi) {
                accg[mi][ni] = __builtin_amdgcn_mfma_f32_16x16x32_bf16(af[mi], b1, accg[mi][ni], 0, 0, 0);
                accu[mi][ni] = __builtin_amdgcn_mfma_f32_16x16x32_bf16(af[mi], b2, accu[mi][ni], 0, 0, 0);
            }
        }
        __syncthreads();
    }

    // ---- epilogue: silu(g)*u -> bf16 h
    int colb = c0 + wc + (lane & 15);
    #pragma unroll
    for (int mi = 0; mi < 4; ++mi) {
        #pragma unroll
        for (int q2 = 0; q2 < 4; ++q2) {
            int r = r0 + wr + mi * 16 + (lane >> 4) * 4 + q2;
            if (r >= ce) continue;
            ushort* hp = h + (size_t)(base + r) * INTER + colb;
            #pragma unroll
            for (int ni = 0; ni < 4; ++ni) {
                float gg = accg[mi][ni][q2];
                float uu = accu[mi][ni][q2];
                float s = gg / (1.f + __expf(-gg));
                hp[ni * 16] = f2bf(s * uu);
            }
        }
    }
}

// ---------------- ffn2: y = wgt * (h @ w2), bf16 MFMA -----------------------
__global__ __launch_bounds__(256, 2) void ffn2_kernel(
        const ushort* __restrict__ h,
        const float* __restrict__ w2,
        const int* __restrict__ cnt, const int* __restrict__ pbase,
        const float* __restrict__ wgtl,
        ushort* __restrict__ y) {
    // decode: group = colblock + 16*expert (128 groups), same-XCD members
    int d   = blockIdx.x;
    int xcd = d & 7;
    int q   = d >> 3;
    int gq  = q / NRB;
    int rb  = q % NRB;
    int g   = gq * 8 + xcd;
    int cb  = g & 15;          // 16 colblocks
    int e   = g >> 4;          // expert

    int ce = cnt[e];
    int r0 = rb * BM;
    if (r0 >= ce) return;
    int base = pbase[e];
    int c0   = cb * BN;

    __shared__ ushort As[BM * LSTR];
    __shared__ ushort Bs[BN * LSTR];

    int tid  = threadIdx.x;
    int lane = tid & 63;
    int wid  = tid >> 6;
    int wr   = (wid >> 1) * 64;
    int wc   = (wid & 1)  * 64;

    // A staging: h is already bf16; 4 threads x 16B per row, 64 rows/pass
    int ar = tid >> 2;                    // 0..63
    int ak = (tid & 3) * 8;               // 0,8,16,24 (elements)
    const ushort* hr[2]; bool av[2];
    #pragma unroll
    for (int mi = 0; mi < 2; ++mi) {
        int r = r0 + ar + 64 * mi;
        av[mi] = (r < ce);
        hr[mi] = h + (size_t)(base + r) * INTER + ak;
    }
    int bn = tid & 127;
    int bg = (tid >> 7) * 8;
    const float* w2p = w2 + (size_t)e * INTER * HID + c0 + bn;

    f32x4 acc[4][4];
    #pragma unroll
    for (int i = 0; i < 4; ++i)
        #pragma unroll
        for (int j = 0; j < 4; ++j) acc[i][j] = (f32x4)0.f;

    for (int k0 = 0; k0 < INTER; k0 += BK) {
        #pragma unroll
        for (int mi = 0; mi < 2; ++mi) {
            uint4 v = make_uint4(0, 0, 0, 0);
            if (av[mi]) v = *reinterpret_cast<const uint4*>(hr[mi] + k0);
            *reinterpret_cast<uint4*>(&As[(ar + 64 * mi) * LSTR + ak]) = v;
        }
        #pragma unroll
        for (int g2 = 0; g2 < 2; ++g2) {
            int kk = k0 + g2 * 16 + bg;
            const float* p = w2p + (size_t)kk * HID;
            ushort8v t;
            #pragma unroll
            for (int j = 0; j < 8; ++j) t[j] = f2bf(p[(size_t)j * HID]);
            *reinterpret_cast<ushort8v*>(&Bs[bn * LSTR + g2 * 16 + bg]) = t;
        }
        __syncthreads();
        int arow = wr + (lane & 15);
        int koff = (lane >> 4) * 8;
        short8 af[4];
        #pragma unroll
        for (int mi = 0; mi < 4; ++mi)
            af[mi] = *reinterpret_cast<const short8*>(&As[(arow + mi * 16) * LSTR + koff]);
        #pragma unroll
        for (int ni = 0; ni < 4; ++ni) {
            int brow = wc + ni * 16 + (lane & 15);
            short8 b = *reinterpret_cast<const short8*>(&Bs[brow * LSTR + koff]);
            #pragma unroll
            for (int mi = 0; mi < 4; ++mi)
                acc[mi][ni] = __builtin_amdgcn_mfma_f32_16x16x32_bf16(af[mi], b, acc[mi][ni], 0, 0, 0);
        }
        __syncthreads();
    }

    int colb = c0 + wc + (lane & 15);
    #pragma unroll
    for (int mi = 0; mi < 4; ++mi) {
        #pragma unroll
        for (int q2 = 0; q2 < 4; ++q2) {
            int r = r0 + wr + mi * 16 + (lane >> 4) * 4 + q2;
            if (r >= ce) continue;
            float wv = wgtl[base + r];
            ushort* yp = y + (size_t)(base + r) * HID + colb;
            #pragma unroll
            for (int ni = 0; ni < 4; ++ni)
                yp[ni * 16] = f2bf(wv * acc[mi][ni][q2]);
        }
    }
}

// ---------------- combine: out[t] = y[row(t,0)] + y[row(t,1)] --------------
__global__ __launch_bounds__(256) void combine_kernel(
        const ushort* __restrict__ y, const int* __restrict__ pairrow,
        float* __restrict__ out) {
    int t = blockIdx.x;
    const ushort* y0 = y + (size_t)pairrow[2 * t] * HID;
    const ushort* y1 = y + (size_t)pairrow[2 * t + 1] * HID;
    float* op = out + (size_t)t * HID;
    int c = threadIdx.x * 8;
    uint4 a = *reinterpret_cast<const uint4*>(y0 + c);
    uint4 b = *reinterpret_cast<const uint4*>(y1 + c);
    const uint* au = reinterpret_cast<const uint*>(&a);
    const uint* bu = reinterpret_cast<const uint*>(&b);
    #pragma unroll
    for (int i = 0; i < 4; ++i) {
        float alo = __builtin_bit_cast(float, au[i] << 16);
        float ahi = __builtin_bit_cast(float, au[i] & 0xffff0000u);
        float blo = __builtin_bit_cast(float, bu[i] << 16);
        float bhi = __builtin_bit_cast(float, bu[i] & 0xffff0000u);
        op[c + 2 * i]     = alo + blo;
        op[c + 2 * i + 1] = ahi + bhi;
    }
}

extern "C" void kernel_launch(void* const* d_in, const int* in_sizes, int n_in,
                              void* d_out, int out_size, void* d_ws, size_t ws_size,
                              hipStream_t stream) {
    (void)in_sizes; (void)n_in; (void)out_size; (void)ws_size;
    const float* x   = (const float*)d_in[0];
    const float* ew  = (const float*)d_in[1];
    const float* w1  = (const float*)d_in[2];
    const float* w2  = (const float*)d_in[3];
    const float* w3  = (const float*)d_in[4];
    const int*  eidx = (const int*)d_in[5];
    float* out = (float*)d_out;

    int*   cnt     = (int*)d_ws;
    int*   pbase   = cnt + 8;                 // 9 entries
    int*   tokl    = cnt + 32;                // MAXROWS
    float* wgtl    = (float*)(tokl + MAXROWS);
    int*   pairrow = (int*)(wgtl + MAXROWS);  // NPAIRS
    ushort* h = (ushort*)((((uintptr_t)(pairrow + NPAIRS)) + 255) & ~(uintptr_t)255);
    ushort* y = h + (size_t)MAXROWS * INTER;  // total ws use ~113.5 MB

    route_kernel<<<1, 256, 0, stream>>>(eidx, ew, cnt, pbase, tokl, wgtl, pairrow);
    ffn1_kernel<<<NRB * (INTER / BN) * NEXP, 256, 0, stream>>>(
        x, w1, w3, cnt, pbase, tokl, h);
    ffn2_kernel<<<NRB * (HID / BN) * NEXP, 256, 0, stream>>>(
        h, w2, cnt, pbase, wgtl, y);
    combine_kernel<<<T_TOKENS, 256, 0, stream>>>(y, pairrow, out);
}

// Round 6
// 855.229 us; speedup vs baseline: 7.3839x; 1.5526x over previous
//
#include <hip/hip_runtime.h>
#include <hip/hip_bf16.h>
#include <cstdint>

// MoEExperts: x[4096,2048] f32, top-2 of 8 experts,
// w1/w3 [8,2048,4096] (K-major [K][N]), w2 [8,4096,2048], out [4096,2048] f32.
#define T_TOKENS 4096
#define HID      2048
#define INTER    4096
#define NEXP     8
#define TOPK     2
#define NPAIRS   (T_TOKENS * TOPK)          // 8192
#define BM 128
#define BN 128
#define BK 32
#define MAXROWS  (NPAIRS + NEXP * BM)       // 9216
#define NRB1     64                          // worst-case per-expert row-blocks

typedef __attribute__((ext_vector_type(8))) short   short8;
typedef __attribute__((ext_vector_type(4))) float   f32x4;
typedef __attribute__((ext_vector_type(8))) ushort  ushort8v;

static __device__ __forceinline__ ushort f2bf(float f) {
    __hip_bfloat16 b = __float2bfloat16(f);
    return __builtin_bit_cast(ushort, b);
}

// global -> LDS async copy, 16B per lane; dest = uniform base + lane*16
typedef const __attribute__((address_space(1))) unsigned char ga_u8;
typedef __attribute__((address_space(3))) unsigned char       la_u8;
static __device__ __forceinline__ void gl_lds16(const void* g, void* l) {
    __builtin_amdgcn_global_load_lds((ga_u8*)g, (la_u8*)l, 16, 0, 0);
}

// ---------------- routing -------------------------------------------------
__global__ void route_kernel(const int* __restrict__ eidx,
                             const float* __restrict__ ew,
                             int* __restrict__ cnt, int* __restrict__ pbase,
                             int* __restrict__ tokl, float* __restrict__ wgtl,
                             int* __restrict__ pairrow) {
    __shared__ int s_cnt[NEXP];
    __shared__ int s_pos[NEXP];
    __shared__ int s_base[NEXP];
    int tid = threadIdx.x;
    if (tid < NEXP) { s_cnt[tid] = 0; s_pos[tid] = 0; }
    __syncthreads();
    for (int p = tid; p < NPAIRS; p += blockDim.x)
        atomicAdd(&s_cnt[eidx[p]], 1);
    __syncthreads();
    if (tid == 0) {
        int b = 0;
        for (int e = 0; e < NEXP; ++e) {
            s_base[e] = b;
            cnt[e]    = s_cnt[e];
            pbase[e]  = b;
            b += (s_cnt[e] + BM - 1) / BM * BM;
        }
        pbase[NEXP] = b;
    }
    __syncthreads();
    for (int p = tid; p < NPAIRS; p += blockDim.x) {
        int e   = eidx[p];
        int pos = atomicAdd(&s_pos[e], 1);
        int row = s_base[e] + pos;
        tokl[row]  = p >> 1;
        wgtl[row]  = ew[p];
        pairrow[p] = row;
    }
}

// ---------------- x fp32 -> bf16 ------------------------------------------
__global__ __launch_bounds__(256) void cvt_x_kernel(const float* __restrict__ x,
                                                    ushort* __restrict__ xbf) {
    int i = (blockIdx.x * 256 + threadIdx.x) * 8;
    float4 a = *reinterpret_cast<const float4*>(x + i);
    float4 b = *reinterpret_cast<const float4*>(x + i + 4);
    ushort8v o;
    o[0] = f2bf(a.x); o[1] = f2bf(a.y); o[2] = f2bf(a.z); o[3] = f2bf(a.w);
    o[4] = f2bf(b.x); o[5] = f2bf(b.y); o[6] = f2bf(b.z); o[7] = f2bf(b.w);
    *reinterpret_cast<ushort8v*>(xbf + i) = o;
}

// ---------------- weight transpose+convert: fp32 [K][N] -> bf16 [N][K] -----
// dst region layout: [gridz][CN][K]; cols [c0, c0+CN) of src.
__global__ __launch_bounds__(256) void transpose_cvt_kernel(
        const float* __restrict__ src, ushort* __restrict__ dst,
        int K, int N, int c0, int CN, long estride) {
    int ez = blockIdx.z;
    const float* s = src + (size_t)ez * estride;
    ushort* d = dst + (size_t)ez * CN * K;
    int nb = blockIdx.x * 64 + c0;
    int kb = blockIdx.y * 64;
    __shared__ ushort t[64][72];
    int tid = threadIdx.x;
    int kr = tid >> 2;
    int ns = tid & 3;
    #pragma unroll
    for (int p = 0; p < 4; ++p) {
        int f = ns + p * 4;                 // float4 index 0..15
        float4 v = *reinterpret_cast<const float4*>(&s[(size_t)(kb + kr) * N + nb + f * 4]);
        t[f * 4 + 0][kr] = f2bf(v.x);
        t[f * 4 + 1][kr] = f2bf(v.y);
        t[f * 4 + 2][kr] = f2bf(v.z);
        t[f * 4 + 3][kr] = f2bf(v.w);
    }
    __syncthreads();
    int nr = tid >> 2;
    #pragma unroll
    for (int p = 0; p < 2; ++p) {
        int ks = ((tid & 3) + p * 4) * 8;   // 0..56
        ushort8v v8 = *reinterpret_cast<const ushort8v*>(&t[nr][ks]);
        *reinterpret_cast<ushort8v*>(&d[(size_t)(nb - c0 + nr) * K + kb + ks]) = v8;
    }
}

// swizzle helper: v(r) spreads 16B slots across banks; bijective per row
#define SWZV(r) (((r) & 3) ^ (((r) >> 2) & 3))

// ---------------- ffn1: h = silu(x@w1) * (x@w3) ----------------------------
#define F1_LDSB 24576   // per dbuf: A 8KB + B1 8KB + B3 8KB
__global__ __launch_bounds__(256, 2) void ffn1_kernel(
        const ushort* __restrict__ xbf,
        const ushort* __restrict__ wT1, const ushort* __restrict__ wT3,
        const int* __restrict__ cnt, const int* __restrict__ pbase,
        const int* __restrict__ tokl, ushort* __restrict__ h,
        int e0, int CN, int c0) {
    int d = blockIdx.x;
    int xcd = d & 7, q = d >> 3;
    int gq = q / NRB1, rb = q % NRB1;
    int ncb = CN >> 7;
    int g = gq * 8 + xcd;
    int ez = g / ncb, cb = g - ez * ncb;
    int e = e0 + ez;
    int ce = cnt[e];
    int r0 = rb * BM;
    if (r0 >= ce) return;
    int base = pbase[e];

    __shared__ ushort ldsbuf[2 * F1_LDSB / 2];
    int tid = threadIdx.x, lane = tid & 63, wid = tid >> 6;
    int wr = (wid >> 1) * 64, wc = (wid & 1) * 64;

    // staging: wave wid covers tile rows [wid*32, wid*32+32), 2 instrs
    int t0 = wid * 32 + (lane >> 2);
    int t1 = t0 + 16;
    int sw0 = (((lane & 3) ^ SWZV(t0)) << 4);
    int sw1 = (((lane & 3) ^ SWZV(t1)) << 4);
    int cr0 = r0 + t0, cr1 = r0 + t1;
    const char* aS0 = (const char*)(xbf + (size_t)tokl[base + (cr0 < ce ? cr0 : 0)] * HID) + sw0;
    const char* aS1 = (const char*)(xbf + (size_t)tokl[base + (cr1 < ce ? cr1 : 0)] * HID) + sw1;
    const ushort* B1g = wT1 + ((size_t)ez * CN + (size_t)cb * 128) * HID;
    const ushort* B3g = wT3 + ((size_t)ez * CN + (size_t)cb * 128) * HID;
    const char* b1S0 = (const char*)(B1g + (size_t)t0 * HID) + sw0;
    const char* b1S1 = (const char*)(B1g + (size_t)t1 * HID) + sw1;
    const char* b3S0 = (const char*)(B3g + (size_t)t0 * HID) + sw0;
    const char* b3S1 = (const char*)(B3g + (size_t)t1 * HID) + sw1;

    char* Lb = (char*)ldsbuf;
    int dst0 = wid * 2048;

    int vl = SWZV(lane & 15);
    int fs = (((lane >> 4) ^ vl) << 4);
    int aoff[4], boff[4];
    #pragma unroll
    for (int i = 0; i < 4; ++i) {
        aoff[i] = (wr + i * 16 + (lane & 15)) * 64 + fs;
        boff[i] = (wc + i * 16 + (lane & 15)) * 64 + fs;
    }

    f32x4 accg[4][4], accu[4][4];
    #pragma unroll
    for (int i = 0; i < 4; ++i)
        #pragma unroll
        for (int j = 0; j < 4; ++j) { accg[i][j] = (f32x4)0.f; accu[i][j] = (f32x4)0.f; }

    auto stage = [&](int buf, int t) {
        char* L = Lb + buf * F1_LDSB;
        int adv = t * 64;
        gl_lds16(aS0 + adv,  L + dst0);
        gl_lds16(aS1 + adv,  L + dst0 + 1024);
        gl_lds16(b1S0 + adv, L + 8192 + dst0);
        gl_lds16(b1S1 + adv, L + 8192 + dst0 + 1024);
        gl_lds16(b3S0 + adv, L + 16384 + dst0);
        gl_lds16(b3S1 + adv, L + 16384 + dst0 + 1024);
    };

    stage(0, 0);
    __syncthreads();
    const int NT = HID / BK;
    for (int t = 0; t < NT; ++t) {
        int cur = t & 1;
        if (t + 1 < NT) stage(cur ^ 1, t + 1);
        const char* L = Lb + cur * F1_LDSB;
        short8 af[4];
        #pragma unroll
        for (int mi = 0; mi < 4; ++mi)
            af[mi] = *reinterpret_cast<const short8*>(L + aoff[mi]);
        #pragma unroll
        for (int ni = 0; ni < 4; ++ni) {
            short8 b1 = *reinterpret_cast<const short8*>(L + 8192 + boff[ni]);
            short8 b3 = *reinterpret_cast<const short8*>(L + 16384 + boff[ni]);
            #pragma unroll
            for (int mi = 0; mi < 4; ++mi) {
                accg[mi][ni] = __builtin_amdgcn_mfma_f32_16x16x32_bf16(af[mi], b1, accg[mi][ni], 0, 0, 0);
                accu[mi][ni] = __builtin_amdgcn_mfma_f32_16x16x32_bf16(af[mi], b3, accu[mi][ni], 0, 0, 0);
            }
        }
        __syncthreads();
    }

    int hcol = c0 + cb * 128 + wc + (lane & 15);
    #pragma unroll
    for (int mi = 0; mi < 4; ++mi) {
        #pragma unroll
        for (int q2 = 0; q2 < 4; ++q2) {
            int r = r0 + wr + mi * 16 + (lane >> 4) * 4 + q2;
            if (r >= ce) continue;
            ushort* hp = h + (size_t)(base + r) * INTER + hcol;
            #pragma unroll
            for (int ni = 0; ni < 4; ++ni) {
                float gg = accg[mi][ni][q2];
                float uu = accu[mi][ni][q2];
                float s = gg / (1.f + __expf(-gg));
                hp[ni * 16] = f2bf(s * uu);
            }
        }
    }
}

// ---------------- ffn2: y = wgt * (h @ w2) ---------------------------------
#define F2_LDSB 16384   // per dbuf: A 8KB + B 8KB
__global__ __launch_bounds__(256, 3) void ffn2_kernel(
        const ushort* __restrict__ h,
        const ushort* __restrict__ wT2,
        const int* __restrict__ cnt, const int* __restrict__ pbase,
        const float* __restrict__ wgtl, ushort* __restrict__ y,
        int e0, int CN, int c0) {
    int d = blockIdx.x;
    int xcd = d & 7, q = d >> 3;
    int gq = q / NRB1, rb = q % NRB1;
    int ncb = CN >> 7;
    int g = gq * 8 + xcd;
    int ez = g / ncb, cb = g - ez * ncb;
    int e = e0 + ez;
    int ce = cnt[e];
    int r0 = rb * BM;
    if (r0 >= ce) return;
    int base = pbase[e];

    __shared__ ushort ldsbuf[2 * F2_LDSB / 2];
    int tid = threadIdx.x, lane = tid & 63, wid = tid >> 6;
    int wr = (wid >> 1) * 64, wc = (wid & 1) * 64;

    int t0 = wid * 32 + (lane >> 2);
    int t1 = t0 + 16;
    int sw0 = (((lane & 3) ^ SWZV(t0)) << 4);
    int sw1 = (((lane & 3) ^ SWZV(t1)) << 4);
    int cr0 = r0 + t0, cr1 = r0 + t1;
    const char* aS0 = (const char*)(h + (size_t)(base + (cr0 < ce ? cr0 : 0)) * INTER) + sw0;
    const char* aS1 = (const char*)(h + (size_t)(base + (cr1 < ce ? cr1 : 0)) * INTER) + sw1;
    const ushort* Bg = wT2 + ((size_t)ez * CN + (size_t)cb * 128) * INTER;
    const char* bS0 = (const char*)(Bg + (size_t)t0 * INTER) + sw0;
    const char* bS1 = (const char*)(Bg + (size_t)t1 * INTER) + sw1;

    char* Lb = (char*)ldsbuf;
    int dst0 = wid * 2048;

    int vl = SWZV(lane & 15);
    int fs = (((lane >> 4) ^ vl) << 4);
    int aoff[4], boff[4];
    #pragma unroll
    for (int i = 0; i < 4; ++i) {
        aoff[i] = (wr + i * 16 + (lane & 15)) * 64 + fs;
        boff[i] = (wc + i * 16 + (lane & 15)) * 64 + fs;
    }

    f32x4 acc[4][4];
    #pragma unroll
    for (int i = 0; i < 4; ++i)
        #pragma unroll
        for (int j = 0; j < 4; ++j) acc[i][j] = (f32x4)0.f;

    auto stage = [&](int buf, int t) {
        char* L = Lb + buf * F2_LDSB;
        int adv = t * 64;
        gl_lds16(aS0 + adv, L + dst0);
        gl_lds16(aS1 + adv, L + dst0 + 1024);
        gl_lds16(bS0 + adv, L + 8192 + dst0);
        gl_lds16(bS1 + adv, L + 8192 + dst0 + 1024);
    };

    stage(0, 0);
    __syncthreads();
    const int NT = INTER / BK;
    for (int t = 0; t < NT; ++t) {
        int cur = t & 1;
        if (t + 1 < NT) stage(cur ^ 1, t + 1);
        const char* L = Lb + cur * F2_LDSB;
        short8 af[4];
        #pragma unroll
        for (int mi = 0; mi < 4; ++mi)
            af[mi] = *reinterpret_cast<const short8*>(L + aoff[mi]);
        #pragma unroll
        for (int ni = 0; ni < 4; ++ni) {
            short8 b = *reinterpret_cast<const short8*>(L + 8192 + boff[ni]);
            #pragma unroll
            for (int mi = 0; mi < 4; ++mi)
                acc[mi][ni] = __builtin_amdgcn_mfma_f32_16x16x32_bf16(af[mi], b, acc[mi][ni], 0, 0, 0);
        }
        __syncthreads();
    }

    int ycol = c0 + cb * 128 + wc + (lane & 15);
    #pragma unroll
    for (int mi = 0; mi < 4; ++mi) {
        #pragma unroll
        for (int q2 = 0; q2 < 4; ++q2) {
            int r = r0 + wr + mi * 16 + (lane >> 4) * 4 + q2;
            if (r >= ce) continue;
            float wv = wgtl[base + r];
            ushort* yp = y + (size_t)(base + r) * HID + ycol;
            #pragma unroll
            for (int ni = 0; ni < 4; ++ni)
                yp[ni * 16] = f2bf(wv * acc[mi][ni][q2]);
        }
    }
}

// ---------------- combine --------------------------------------------------
__global__ __launch_bounds__(256) void combine_kernel(
        const ushort* __restrict__ y, const int* __restrict__ pairrow,
        float* __restrict__ out) {
    int t = blockIdx.x;
    const ushort* y0 = y + (size_t)pairrow[2 * t] * HID;
    const ushort* y1 = y + (size_t)pairrow[2 * t + 1] * HID;
    float* op = out + (size_t)t * HID;
    int c = threadIdx.x * 8;
    uint4 a = *reinterpret_cast<const uint4*>(y0 + c);
    uint4 b = *reinterpret_cast<const uint4*>(y1 + c);
    const uint* au = reinterpret_cast<const uint*>(&a);
    const uint* bu = reinterpret_cast<const uint*>(&b);
    #pragma unroll
    for (int i = 0; i < 4; ++i) {
        float alo = __builtin_bit_cast(float, au[i] << 16);
        float ahi = __builtin_bit_cast(float, au[i] & 0xffff0000u);
        float blo = __builtin_bit_cast(float, bu[i] << 16);
        float bhi = __builtin_bit_cast(float, bu[i] & 0xffff0000u);
        op[c + 2 * i]     = alo + blo;
        op[c + 2 * i + 1] = ahi + bhi;
    }
}

extern "C" void kernel_launch(void* const* d_in, const int* in_sizes, int n_in,
                              void* d_out, int out_size, void* d_ws, size_t ws_size,
                              hipStream_t stream) {
    (void)in_sizes; (void)n_in; (void)out_size;
    const float* x   = (const float*)d_in[0];
    const float* ew  = (const float*)d_in[1];
    const float* w1  = (const float*)d_in[2];
    const float* w2  = (const float*)d_in[3];
    const float* w3  = (const float*)d_in[4];
    const int*  eidx = (const int*)d_in[5];
    float* out = (float*)d_out;

    int*   cnt     = (int*)d_ws;
    int*   pbase   = cnt + 8;
    int*   tokl    = cnt + 32;
    float* wgtl    = (float*)(tokl + MAXROWS);
    int*   pairrow = (int*)(wgtl + MAXROWS);
    ushort* xbf = (ushort*)((((uintptr_t)(pairrow + NPAIRS)) + 255) & ~(uintptr_t)255);
    ushort* h   = xbf + (size_t)T_TOKENS * HID;
    ushort* y   = h + (size_t)MAXROWS * INTER;
    ushort* region = y + (size_t)MAXROWS * HID;
    size_t region_bytes = ws_size - ((char*)region - (char*)d_ws);

    route_kernel<<<1, 256, 0, stream>>>(eidx, ew, cnt, pbase, tokl, wgtl, pairrow);
    cvt_x_kernel<<<T_TOKENS * HID / 8 / 256, 256, 0, stream>>>(x, xbf);

    const size_t per_e1 = (size_t)2 * INTER * HID * 2;   // 33.55 MB (w1T+w3T, one expert)
    const size_t per_e2 = (size_t)HID * INTER * 2;       // 16.78 MB (w2T, one expert)

    // ---- stage 1: transpose w1/w3 + ffn1 ----
    if (region_bytes >= per_e1) {
        int EG = (int)(region_bytes / per_e1); if (EG > 8) EG = 8;
        for (int g = 0; g < NEXP; g += EG) {
            int ne = (NEXP - g < EG) ? (NEXP - g) : EG;
            ushort* wt1 = region;
            ushort* wt3 = region + (size_t)ne * INTER * HID;
            transpose_cvt_kernel<<<dim3(INTER / 64, HID / 64, ne), 256, 0, stream>>>(
                w1 + (size_t)g * HID * INTER, wt1, HID, INTER, 0, INTER, (long)HID * INTER);
            transpose_cvt_kernel<<<dim3(INTER / 64, HID / 64, ne), 256, 0, stream>>>(
                w3 + (size_t)g * HID * INTER, wt3, HID, INTER, 0, INTER, (long)HID * INTER);
            ffn1_kernel<<<NRB1 * ne * (INTER / BN), 256, 0, stream>>>(
                xbf, wt1, wt3, cnt, pbase, tokl, h, g, INTER, 0);
        }
    } else {
        const int CN = 1024;
        for (int e = 0; e < NEXP; ++e) {
            for (int c = 0; c < INTER; c += CN) {
                ushort* wt1 = region;
                ushort* wt3 = region + (size_t)CN * HID;
                transpose_cvt_kernel<<<dim3(CN / 64, HID / 64, 1), 256, 0, stream>>>(
                    w1 + (size_t)e * HID * INTER, wt1, HID, INTER, c, CN, (long)HID * INTER);
                transpose_cvt_kernel<<<dim3(CN / 64, HID / 64, 1), 256, 0, stream>>>(
                    w3 + (size_t)e * HID * INTER, wt3, HID, INTER, c, CN, (long)HID * INTER);
                ffn1_kernel<<<NRB1 * (CN / BN), 256, 0, stream>>>(
                    xbf, wt1, wt3, cnt, pbase, tokl, h, e, CN, c);
            }
        }
    }

    // ---- stage 2: transpose w2 + ffn2 ----
    if (region_bytes >= per_e2) {
        int EG = (int)(region_bytes / per_e2); if (EG > 8) EG = 8;
        for (int g = 0; g < NEXP; g += EG) {
            int ne = (NEXP - g < EG) ? (NEXP - g) : EG;
            ushort* wt2 = region;
            transpose_cvt_kernel<<<dim3(HID / 64, INTER / 64, ne), 256, 0, stream>>>(
                w2 + (size_t)g * INTER * HID, wt2, INTER, HID, 0, HID, (long)INTER * HID);
            ffn2_kernel<<<NRB1 * ne * (HID / BN), 256, 0, stream>>>(
                h, wt2, cnt, pbase, wgtl, y, g, HID, 0);
        }
    } else {
        const int CN = 1024;
        for (int e = 0; e < NEXP; ++e) {
            for (int c = 0; c < HID; c += CN) {
                ushort* wt2 = region;
                transpose_cvt_kernel<<<dim3(CN / 64, INTER / 64, 1), 256, 0, stream>>>(
                    w2 + (size_t)e * INTER * HID, wt2, INTER, HID, c, CN, (long)INTER * HID);
                ffn2_kernel<<<NRB1 * (CN / BN), 256, 0, stream>>>(
                    h, wt2, cnt, pbase, wgtl, y, e, CN, c);
            }
        }
    }

    combine_kernel<<<T_TOKENS, 256, 0, stream>>>(y, pairrow, out);
}